// Round 9
// baseline (191.995 us; speedup 1.0000x reference)
//
#include <hip/hip_runtime.h>

// YOLO-v1 loss, fp32, N=16384, S=7, B=2, C=20 → 30 floats/cell, 802816 cells.
// R9: R8 (NT loads broke the 2.7 TB/s L2-fill plateau; kernel <56 µs) +
// register staging to double per-wave MLP: issue ALL 16 NT float4 loads
// (pred+target) back-to-back into 16 VGPR quads, then LDS round-trip pred,
// then target from regs (no global dependency left → no mid-tile drain).
// One 7.68 KB wave-private LDS region, BLK=256 → ~30.7 KB/block, 5 blk/CU.

typedef float vfloat4 __attribute__((ext_vector_type(4)));

constexpr int S = 7;
constexpr int FPC = 30;           // floats per cell
constexpr int BLK = 256;          // 4 waves
constexpr int WAVES = BLK / 64;
constexpr int TILE_F4 = 64 * FPC / 4;   // 480 float4 per wave tile
constexpr float STEP = 1.0f / 7.0f;
constexpr float EPS = 1e-10f;

__global__ __launch_bounds__(BLK) void yolo_partial_kernel(
    const float* __restrict__ pred,
    const float* __restrict__ target,
    float* __restrict__ partial) {
  __shared__ float lds[WAVES][64 * FPC];   // 7680 B per wave region
  __shared__ float wsum[WAVES];

  const int tid = threadIdx.x;
  const int lane = tid & 63;
  const int wid = tid >> 6;
  const int cellw = blockIdx.x * BLK + wid * 64;  // wave's first cell
  const int cell = cellw + lane;

  float* myld = lds[wid];
  vfloat4* l4 = (vfloat4*)myld;
  union Buf { float2 v[FPC / 2]; float f[FPC]; };
  Buf P, T;

  // ---- issue ALL 16 NT loads back-to-back (8 pred + 8 target) ----
  const vfloat4* gp = (const vfloat4*)(pred + (size_t)cellw * FPC);
  const vfloat4* gt = (const vfloat4*)(target + (size_t)cellw * FPC);
  vfloat4 rp[8], rt[8];
  #pragma unroll
  for (int i = 0; i < 8; ++i) {
    int idx = i * 64 + lane;
    if (idx < TILE_F4) rp[i] = __builtin_nontemporal_load(gp + idx);
  }
  #pragma unroll
  for (int i = 0; i < 8; ++i) {
    int idx = i * 64 + lane;
    if (idx < TILE_F4) rt[i] = __builtin_nontemporal_load(gt + idx);
  }

  // ---- pred: regs → LDS → per-cell regs (DS in-order within wave) ----
  #pragma unroll
  for (int i = 0; i < 8; ++i) {
    int idx = i * 64 + lane;
    if (idx < TILE_F4) l4[idx] = rp[i];
  }
  {
    const float2* l2 = (const float2*)(myld + lane * FPC);
    #pragma unroll
    for (int i = 0; i < FPC / 2; ++i) P.v[i] = l2[i];
  }
  asm volatile("" ::: "memory");  // keep target writes after pred reads
  // ---- target into the SAME region, from regs (no global dep) ----
  #pragma unroll
  for (int i = 0; i < 8; ++i) {
    int idx = i * 64 + lane;
    if (idx < TILE_F4) l4[idx] = rt[i];
  }
  {
    const float2* l2 = (const float2*)(myld + lane * FPC);
    #pragma unroll
    for (int i = 0; i < FPC / 2; ++i) T.v[i] = l2[i];
  }

  const float* p = P.f;
  const float* t = T.f;

  // ---- per-cell loss ----
  const float gx = (float)(cell % S);
  const float gy = (float)((cell / S) % S);
  const float mask = (t[9] > 0.0f) ? 1.0f : 0.0f;

  float iou[2];
  #pragma unroll
  for (int b = 0; b < 2; ++b) {
    const float* pb = p + 5 * b;
    const float* tb = t + 5 * b;
    // _convert_boxes: x0=(x+gx)*STEP - w/2, clip all 4 at 0
    float px = fmaxf((pb[0] + gx) * STEP - pb[2] * 0.5f, 0.0f);
    float py = fmaxf((pb[1] + gy) * STEP - pb[3] * 0.5f, 0.0f);
    float pw = fmaxf(pb[2], 0.0f);
    float ph = fmaxf(pb[3], 0.0f);
    float tx = fmaxf((tb[0] + gx) * STEP - tb[2] * 0.5f, 0.0f);
    float ty = fmaxf((tb[1] + gy) * STEP - tb[3] * 0.5f, 0.0f);
    float tw = fmaxf(tb[2], 0.0f);
    float th = fmaxf(tb[3], 0.0f);
    float iw = fmaxf(pw + tw - (fmaxf(px + pw, tx + tw) - fminf(px, tx)), 0.0f);
    float ih = fmaxf(ph + th - (fmaxf(py + ph, ty + th) - fminf(py, ty)), 0.0f);
    float inter = iw * ih;
    float uni = pw * ph + tw * th - inter;
    iou[b] = inter / (uni + EPS);
  }
  // jnp.argmax: first max wins → box 0 on tie
  const int best = (iou[1] > iou[0]) ? 1 : 0;

  float loss = 0.0f;
  #pragma unroll
  for (int b = 0; b < 2; ++b) {
    const float* pb = p + 5 * b;
    const float* tb = t + 5 * b;
    float obj = (b == best) ? mask : 0.0f;
    float d0 = pb[0] - tb[0];
    float d1 = pb[1] - tb[1];
    float d2 = pb[2] - tb[2];
    float d3 = pb[3] - tb[3];
    loss += 5.0f * obj * (d0 * d0 + d1 * d1 + d2 * d2 + d3 * d3);  // coord
    float dc = pb[4] - iou[b];
    loss += obj * dc * dc;                                         // conf
    loss += 0.5f * (1.0f - obj) * pb[4] * pb[4];                   // noobj
  }
  float cls = 0.0f;
  #pragma unroll
  for (int k = 10; k < 30; ++k) {
    float d = p[k] - t[k];
    cls += d * d;
  }
  loss += mask * cls;                                              // class

  // ---- reduce: wave shuffle → LDS → one plain store per block ----
  #pragma unroll
  for (int off = 32; off > 0; off >>= 1)
    loss += __shfl_down(loss, off, 64);
  if ((tid & 63) == 0) wsum[wid] = loss;
  __syncthreads();
  if (tid == 0) {
    float total = 0.0f;
    #pragma unroll
    for (int w = 0; w < WAVES; ++w) total += wsum[w];
    partial[blockIdx.x] = total;          // distinct address — no atomic
  }
}

__global__ __launch_bounds__(256) void yolo_reduce_kernel(
    const float* __restrict__ partial, float* __restrict__ out,
    int n, float invN) {
  __shared__ float wsum[4];
  const int tid = threadIdx.x;
  float s = 0.0f;
  for (int i = tid; i < n; i += 256) s += partial[i];
  #pragma unroll
  for (int off = 32; off > 0; off >>= 1)
    s += __shfl_down(s, off, 64);
  if ((tid & 63) == 0) wsum[tid >> 6] = s;
  __syncthreads();
  if (tid == 0)
    out[0] = (wsum[0] + wsum[1] + wsum[2] + wsum[3]) * invN;
}

extern "C" void kernel_launch(void* const* d_in, const int* in_sizes, int n_in,
                              void* d_out, int out_size, void* d_ws, size_t ws_size,
                              hipStream_t stream) {
  const float* pred = (const float*)d_in[0];
  const float* target = (const float*)d_in[1];
  float* out = (float*)d_out;
  float* partial = (float*)d_ws;             // 3136 floats = 12.5 KB

  const int ncells = in_sizes[0] / FPC;      // 802816
  const int nblocks = ncells / BLK;          // 3136 (exact)
  const float invN = 1.0f / (float)(ncells / (S * S));  // 1/16384

  yolo_partial_kernel<<<nblocks, BLK, 0, stream>>>(pred, target, partial);
  yolo_reduce_kernel<<<1, 256, 0, stream>>>(partial, out, nblocks, invN);
}